// Round 12
// baseline (176.107 us; speedup 1.0000x reference)
//
#include <hip/hip_runtime.h>

typedef unsigned short u16;
typedef unsigned int u32;
typedef short bf16x8 __attribute__((ext_vector_type(8)));
typedef float f32x4 __attribute__((ext_vector_type(4)));
typedef u32 u32x4 __attribute__((ext_vector_type(4)));

#define MFMA16(a, b, c) __builtin_amdgcn_mfma_f32_16x16x32_bf16((a), (b), (c), 0, 0, 0)

__device__ __forceinline__ u16 f2bf(float f) {
  u32 u = __builtin_bit_cast(u32, f);
  u += 0x7FFFu + ((u >> 16) & 1u);
  return (u16)(u >> 16);
}
// packed f32x2 -> bf16x2, round-half-up (R6-proven; ties differ from RNE by
// <=1 ulp, absmax headroom 3x). NOTE (R4 post-mortem): inline-asm
// v_cvt_pk_bf16_f32 produced NaN on this toolchain -- do NOT reintroduce it.
__device__ __forceinline__ u32 pk2bf(float a, float b) {
  u32 ua = __builtin_bit_cast(u32, a) + 0x8000u;
  u32 ub = __builtin_bit_cast(u32, b) + 0x8000u;
  return (ua >> 16) | (ub & 0xFFFF0000u);
}

// ws byte offsets
#define WS_MGF   0         // bf16 [8 jt][64 lane][8 j]      B-frags of M^T   (8192 B)
#define WS_WT1F  8192      // bf16 [8 ot][2 h][4 ks][64][8]  B-frags of Wp1   (65536 B)
#define WS_WT2F  73728     // bf16 [8 mt][4 h][4 ks][64][8]  A-frags of Wp2^T (131072 B)
#define WS_B1    204800    // f32 [128]  bias1 + T0-fold
#define WS_B2    205312    // f32 [128]  bias2 + T0-fold

// NOTE on element order (kc-permutation): within each 32-wide kc chunk, the
// fragment element at (reader lane q, elem j) holds channel
//   c_local = (j>>2)*16 + q*4 + (j&3)
// chosen so the G1 producer's 8 outputs per lane are CONTIGUOUS in LDS
// (one ds_write_b128). WT1F/WT2F below are built with the same order.
__global__ void prep_kernel(const float* __restrict__ adj,
                            const float* __restrict__ adj_bias,
                            const float* __restrict__ w1,
                            const float* __restrict__ b1,
                            const float* __restrict__ w2,
                            const float* __restrict__ b2,
                            char* __restrict__ ws) {
  const int tid = threadIdx.x;
  if (blockIdx.x == 0) {
    __shared__ float sa[1024], Ls[1024], L2s[1024], L3s[1024], sdre[32];
    float bias = adj_bias[0];
    for (int i = tid; i < 1024; i += 256) sa[i] = fmaxf(adj[i] + bias, 0.0f);
    __syncthreads();
    if (tid < 32) {
      float s = 0.0f;
      for (int c = 0; c < 32; ++c) s += sa[tid * 32 + c];
      sdre[tid] = 1.0f / sqrtf(s + 1e-5f);
    }
    __syncthreads();
    for (int i = tid; i < 1024; i += 256) {
      int n = i >> 5, c = i & 31;
      Ls[i] = (n == c ? 1.0f : 0.0f) - sdre[n] * sa[i] * sdre[c];
    }
    __syncthreads();
    for (int i = tid; i < 1024; i += 256) {
      int r = i >> 5, c = i & 31;
      float s = 0.0f;
      for (int m = 0; m < 32; ++m) s += Ls[r * 32 + m] * Ls[m * 32 + c];
      L2s[i] = s;
    }
    __syncthreads();
    for (int i = tid; i < 1024; i += 256) {
      int r = i >> 5, c = i & 31;
      float s = 0.0f;
      for (int m = 0; m < 32; ++m) s += L2s[r * 32 + m] * Ls[m * 32 + c];
      L3s[i] = s;
    }
    __syncthreads();
    // M stacked [128x32]: rows 0-31 I, 32-63 L, 64-95 2L^2-I, 96-127 4L^3-3L.
    // B-fragments of M^T: MGf[jt][lane][j] = M[col=jt*16+(lane&15)][k=(lane>>4)*8+j]
    u16* MGf = (u16*)(ws + WS_MGF);
    for (int i = tid; i < 4096; i += 256) {
      int jt = i >> 9, lane = (i >> 3) & 63, j = i & 7;
      int col = jt * 16 + (lane & 15);
      int k = ((lane >> 4) << 3) + j;
      int kk = col >> 5, np = col & 31;
      float v;
      if (kk == 0)      v = (np == k) ? 1.0f : 0.0f;
      else if (kk == 1) v = Ls[np * 32 + k];
      else if (kk == 2) v = 2.0f * L2s[np * 32 + k] - (np == k ? 1.0f : 0.0f);
      else              v = 4.0f * L3s[np * 32 + k] - 3.0f * Ls[np * 32 + k];
      MGf[i] = f2bf(v);
    }
    float* B1 = (float*)(ws + WS_B1);
    float* B2 = (float*)(ws + WS_B2);
    if (tid < 128) {
      float s = b1[tid];
      for (int c = 0; c < 60; ++c) s += w1[(c * 5) * 128 + tid];
      B1[tid] = s;
    } else {
      int o = tid - 128;
      float s = b2[o];
      for (int c = 0; c < 128; ++c) s += w2[(c * 5) * 128 + o];
      B2[o] = s;
    }
  } else {
    u16* WT1F = (u16*)(ws + WS_WT1F);
    u16* WT2F = (u16*)(ws + WS_WT2F);
    int g = (blockIdx.x - 1) * 256 + tid;
    // WT1F bits: j[0:3) lane[3:9) ks[9:11) h[11:12) ot[12:15)
    // element = w1 at kterm=ks, c = h*32 + (j>>2)*16 + q*4 + (j&3) (0 if c>=60),
    // o = ot*16+(lane&15)   [kc-permuted order]
    for (int i = g; i < 32768; i += 16 * 256) {
      int j = i & 7, lane = (i >> 3) & 63, ks = (i >> 9) & 3;
      int h = (i >> 11) & 1, ot = i >> 12;
      int q = lane >> 4;
      int c = h * 32 + ((j >> 2) << 4) + q * 4 + (j & 3);
      int o = ot * 16 + (lane & 15);
      WT1F[i] = (c < 60) ? f2bf(w1[(c * 5 + ks + 1) * 128 + o]) : (u16)0;
    }
    // WT2F bits: j[0:3) lane[3:9) ks[9:11) h[11:13) mt[13:16)
    // element = w2 at kterm=ks, c2 = h*32 + (j>>2)*16 + q*4 + (j&3),
    // o = mt*16+(lane&15)   [kc-permuted order]
    for (int i = g; i < 65536; i += 16 * 256) {
      int j = i & 7, lane = (i >> 3) & 63, ks = (i >> 9) & 3;
      int h = (i >> 11) & 3, mt = i >> 13;
      int q = lane >> 4;
      int c2 = h * 32 + ((j >> 2) << 4) + q * 4 + (j & 3);
      int o = mt * 16 + (lane & 15);
      WT2F[i] = f2bf(w2[(c2 * 5 + ks + 1) * 128 + o]);
    }
  }
}

// R6-champion structure (2 batches/block, shared weight frags, batch-ILP,
// pipelined G1/einsum, Ht full-rank swizzle) + R11 delta: Y DOUBLE-BUFFER.
// With two Y buffers per batch the writer always targets the buffer the
// current einsum is NOT reading, so the "einsum reads done" barrier per
// chunk disappears: barriers 14 -> 8. Cost: LDS 32768 -> 49152 B -> 3
// blocks/CU (12 waves). Session data says occupancy is a weak lever here
// (R2/R9); barrier-idle ~29 us is the dominant residual. bounds(256,3)
// also raises the reg cap 128->170 (need ~120, so no spill).
// LDS layouts (49152 B, 3 blocks/CU):
//   Xt [64 c][40] u16       pad-stride, 5120 B/batch
//   Ht [128 o][32] u16      slot swizzle ps = s ^ (l15&3) ^ (l15>>2)
//   Y[2] [32 np][128 kc] u16  16B-slot swizzle ps = s ^ (np&7); 8 KB/buf/batch
//   Ht overlays Xt (Xt dead after layer-1 G1); red overlays Ht in epilogue.
__global__ __launch_bounds__(256, 3) void dgcnn_kernel(
    const float* __restrict__ x,
    const char* __restrict__ ws,
    const float* __restrict__ fc_w,
    const float* __restrict__ fc_b,
    float* __restrict__ out) {
  __shared__ __align__(16) char arena[49152];
  u16* XtA = (u16*)arena;             // 5120 B
  u16* XtB = (u16*)(arena + 5120);    // 5120 B
  u16* HtA = (u16*)arena;             // 8192 B (after Xt dead)
  u16* HtB = (u16*)(arena + 8192);    // 8192 B
  u16* Y0A = (u16*)(arena + 16384);   // 8192 B  Y buffer 0, batch A
  u16* Y0B = (u16*)(arena + 24576);   // 8192 B  Y buffer 0, batch B
  u16* Y1A = (u16*)(arena + 32768);   // 8192 B  Y buffer 1, batch A
  u16* Y1B = (u16*)(arena + 40960);   // 8192 B  Y buffer 1, batch B
  float* red = (float*)arena;         // epilogue overlay (Ht dead)

  const u16* MGf  = (const u16*)(ws + WS_MGF);
  const u16* WT1F = (const u16*)(ws + WS_WT1F);
  const u16* WT2F = (const u16*)(ws + WS_WT2F);
  const float* bias1 = (const float*)(ws + WS_B1);
  const float* bias2 = (const float*)(ws + WS_B2);

  const int tid = threadIdx.x;
  const int w = tid >> 6, lane = tid & 63;
  const int l15 = lane & 15, q = lane >> 4;
  const int b0 = blockIdx.x * 2;
  const f32x4 z4 = {0.0f, 0.0f, 0.0f, 0.0f};

  // M^T B-fragments: wave w covers M^T col tiles 2w, 2w+1 (k-term = w)
  bf16x8 mB0 = *(const bf16x8*)(MGf + ((2 * w + 0) * 64 + lane) * 8);
  bf16x8 mB1 = *(const bf16x8*)(MGf + ((2 * w + 1) * 64 + lane) * 8);

  // ---- stage x^T (both batches), coalesced float4 loads, b32 node-pair
  // writes (2-way banks = free). Threads with tc==60 write the zero rows.
  const float* xb = x + (size_t)b0 * 1920;
  {
    int tn = (tid & 15) * 2;   // node pair n, n+1
    int tc = (tid >> 4) * 4;   // channel quad c..c+3
    if (tc < 60) {
      float4 a0 = *(const float4*)(xb + tn * 60 + tc);
      float4 a1 = *(const float4*)(xb + tn * 60 + 60 + tc);
      float4 c0 = *(const float4*)(xb + 1920 + tn * 60 + tc);
      float4 c1 = *(const float4*)(xb + 1920 + tn * 60 + 60 + tc);
      *(u32*)&XtA[(tc + 0) * 40 + tn] = pk2bf(a0.x, a1.x);
      *(u32*)&XtA[(tc + 1) * 40 + tn] = pk2bf(a0.y, a1.y);
      *(u32*)&XtA[(tc + 2) * 40 + tn] = pk2bf(a0.z, a1.z);
      *(u32*)&XtA[(tc + 3) * 40 + tn] = pk2bf(a0.w, a1.w);
      *(u32*)&XtB[(tc + 0) * 40 + tn] = pk2bf(c0.x, c1.x);
      *(u32*)&XtB[(tc + 1) * 40 + tn] = pk2bf(c0.y, c1.y);
      *(u32*)&XtB[(tc + 2) * 40 + tn] = pk2bf(c0.z, c1.z);
      *(u32*)&XtB[(tc + 3) * 40 + tn] = pk2bf(c0.w, c1.w);
    } else {
#pragma unroll
      for (int j = 0; j < 4; ++j) {
        *(u32*)&XtA[(tc + j) * 40 + tn] = 0;
        *(u32*)&XtB[(tc + j) * 40 + tn] = 0;
      }
    }
  }
  __syncthreads();

  // G1 write swizzle: 16B slot (w*4+q) XOR'd with (np&7); same for both jtl.
  const int ysw_w = ((w * 4 + q) ^ (l15 & 7)) * 8;  // u16 units
  const int psr = (q ^ (l15 & 3) ^ (l15 >> 2)) * 8; // Ht read slot (layer 2)

  // G1 pipeline registers: [mtl][ct] as named vars (static indexing, rule #20)
  f32x4 gA00, gA01, gA10, gA11, gB00, gB01, gB10, gB11;
  // Packed Y values (ypk consumes g regs -> 16 regs live across barrier)
  u32x4 yA0, yA1, yB0, yB1;

  // G1-compute from Xt (layer 1), chunk h -> g regs only (no LDS write)
  auto g1c_x = [&](int h) {
    int r0 = ((2 * h + 0) * 16 + l15) * 40 + q * 8;
    int r1 = ((2 * h + 1) * 16 + l15) * 40 + q * 8;
    bf16x8 aA0 = *(const bf16x8*)&XtA[r0];
    bf16x8 aA1 = *(const bf16x8*)&XtA[r1];
    bf16x8 aB0 = *(const bf16x8*)&XtB[r0];
    bf16x8 aB1 = *(const bf16x8*)&XtB[r1];
    gA00 = MFMA16(aA0, mB0, z4); gA01 = MFMA16(aA0, mB1, z4);
    gA10 = MFMA16(aA1, mB0, z4); gA11 = MFMA16(aA1, mB1, z4);
    gB00 = MFMA16(aB0, mB0, z4); gB01 = MFMA16(aB0, mB1, z4);
    gB10 = MFMA16(aB1, mB0, z4); gB11 = MFMA16(aB1, mB1, z4);
  };
  // G1-compute from Ht (layer 2), chunk h
  auto g1c_h = [&](int h) {
    int o20 = ((2 * h + 0) * 16 + l15) * 32 + psr;
    int o21 = ((2 * h + 1) * 16 + l15) * 32 + psr;
    bf16x8 aA0 = *(const bf16x8*)&HtA[o20];
    bf16x8 aA1 = *(const bf16x8*)&HtA[o21];
    bf16x8 aB0 = *(const bf16x8*)&HtB[o20];
    bf16x8 aB1 = *(const bf16x8*)&HtB[o21];
    gA00 = MFMA16(aA0, mB0, z4); gA01 = MFMA16(aA0, mB1, z4);
    gA10 = MFMA16(aA1, mB0, z4); gA11 = MFMA16(aA1, mB1, z4);
    gB00 = MFMA16(aB0, mB0, z4); gB01 = MFMA16(aB0, mB1, z4);
    gB10 = MFMA16(aB1, mB0, z4); gB11 = MFMA16(aB1, mB1, z4);
  };
  // pack g regs -> y regs (pure VALU; scheduled inside the einsum region)
  auto ypk = [&]() {
    yA0 = (u32x4){pk2bf(gA00[0], gA00[1]), pk2bf(gA00[2], gA00[3]),
                  pk2bf(gA10[0], gA10[1]), pk2bf(gA10[2], gA10[3])};
    yB0 = (u32x4){pk2bf(gB00[0], gB00[1]), pk2bf(gB00[2], gB00[3]),
                  pk2bf(gB10[0], gB10[1]), pk2bf(gB10[2], gB10[3])};
    yA1 = (u32x4){pk2bf(gA01[0], gA01[1]), pk2bf(gA01[2], gA01[3]),
                  pk2bf(gA11[0], gA11[1]), pk2bf(gA11[2], gA11[3])};
    yB1 = (u32x4){pk2bf(gB01[0], gB01[1]), pk2bf(gB01[2], gB01[3]),
                  pk2bf(gB11[0], gB11[1]), pk2bf(gB11[2], gB11[3])};
  };
  // store packed y regs into Y buffer b (compile-time b at every call site)
  auto yst = [&](int b) {
    u16* YA = b ? Y1A : Y0A;
    u16* YB = b ? Y1B : Y0B;
    *(u32x4*)&YA[(0 * 16 + l15) * 128 + ysw_w] = yA0;
    *(u32x4*)&YB[(0 * 16 + l15) * 128 + ysw_w] = yB0;
    *(u32x4*)&YA[(1 * 16 + l15) * 128 + ysw_w] = yA1;
    *(u32x4*)&YB[(1 * 16 + l15) * 128 + ysw_w] = yB1;
  };

  // ---------------- layer 1: 2 kc-chunks, Y double-buffered ----------------
  f32x4 acc1A[2][2] = {{z4, z4}, {z4, z4}};  // [nt][ot]
  f32x4 acc1B[2][2] = {{z4, z4}, {z4, z4}};
  auto einsum1 = [&](int h, int b) {
    const u16* YA = b ? Y1A : Y0A;
    const u16* YB = b ? Y1B : Y0B;
    __builtin_amdgcn_s_setprio(1);
#pragma unroll
    for (int ks = 0; ks < 4; ++ks) {
      const u16* wp = WT1F + (size_t)((((2 * w) * 2 + h) * 4 + ks) * 64 + lane) * 8;
      bf16x8 wfa = *(const bf16x8*)wp;
      bf16x8 wfb = *(const bf16x8*)(wp + 4096);  // ot+1
      int ysw = ((ks * 4 + q) ^ (l15 & 7)) * 8;
      bf16x8 a0A = *(const bf16x8*)&YA[l15 * 128 + ysw];
      bf16x8 a1A = *(const bf16x8*)&YA[(16 + l15) * 128 + ysw];
      bf16x8 a0B = *(const bf16x8*)&YB[l15 * 128 + ysw];
      bf16x8 a1B = *(const bf16x8*)&YB[(16 + l15) * 128 + ysw];
      acc1A[0][0] = MFMA16(a0A, wfa, acc1A[0][0]);
      acc1A[0][1] = MFMA16(a0A, wfb, acc1A[0][1]);
      acc1A[1][0] = MFMA16(a1A, wfa, acc1A[1][0]);
      acc1A[1][1] = MFMA16(a1A, wfb, acc1A[1][1]);
      acc1B[0][0] = MFMA16(a0B, wfa, acc1B[0][0]);
      acc1B[0][1] = MFMA16(a0B, wfb, acc1B[0][1]);
      acc1B[1][0] = MFMA16(a1B, wfa, acc1B[1][0]);
      acc1B[1][1] = MFMA16(a1B, wfb, acc1B[1][1]);
    }
    __builtin_amdgcn_s_setprio(0);
  };

  g1c_x(0);
  ypk();
  yst(0);
  __syncthreads();           // B1: Y buf0 visible
  g1c_x(1);                  // overlaps einsum1(0): separate pipes
  ypk();
  einsum1(0, 0);             // reads buf0
  yst(1);                    // writes buf1 -- no conflict with buf0 reads
  __syncthreads();           // B2: buf1 visible
  einsum1(1, 1);

  // bias+relu -> Ht (Xt dead: all waves' Xt reads precede B2; writes follow it)
#pragma unroll
  for (int ot = 0; ot < 2; ++ot) {
    int o = (2 * w + ot) * 16 + l15;
    float bv = bias1[o];
#pragma unroll
    for (int mt = 0; mt < 2; ++mt) {
      // logical n-slot s = mt*2 + (q>>1); physical = s ^ (l15&3) ^ (l15>>2)
      int ps = (mt * 2 + (q >> 1)) ^ (l15 & 3) ^ (l15 >> 2);
      int idx = o * 32 + ps * 8 + (q & 1) * 4;
      uint2 vA, vB;
      vA.x = pk2bf(fmaxf(acc1A[mt][ot][0] + bv, 0.0f), fmaxf(acc1A[mt][ot][1] + bv, 0.0f));
      vA.y = pk2bf(fmaxf(acc1A[mt][ot][2] + bv, 0.0f), fmaxf(acc1A[mt][ot][3] + bv, 0.0f));
      vB.x = pk2bf(fmaxf(acc1B[mt][ot][0] + bv, 0.0f), fmaxf(acc1B[mt][ot][1] + bv, 0.0f));
      vB.y = pk2bf(fmaxf(acc1B[mt][ot][2] + bv, 0.0f), fmaxf(acc1B[mt][ot][3] + bv, 0.0f));
      *(uint2*)&HtA[idx] = vA;
      *(uint2*)&HtB[idx] = vB;
    }
  }
  __syncthreads();           // B3: Ht visible; fences einsum1(1) buf1 reads
                             // and einsum1(0) buf0 reads (rewritten next)

  // ---------------- layer 2: 4 kc-chunks, Y double-buffered ----------------
  f32x4 acc2A[2][2] = {{z4, z4}, {z4, z4}};  // [ot][nt]
  f32x4 acc2B[2][2] = {{z4, z4}, {z4, z4}};
  auto einsum2 = [&](int h, int b) {
    const u16* YA = b ? Y1A : Y0A;
    const u16* YB = b ? Y1B : Y0B;
    __builtin_amdgcn_s_setprio(1);
#pragma unroll
    for (int ks = 0; ks < 4; ++ks) {
      const u16* wp = WT2F + (size_t)((((2 * w) * 4 + h) * 4 + ks) * 64 + lane) * 8;
      bf16x8 wfa = *(const bf16x8*)wp;
      bf16x8 wfb = *(const bf16x8*)(wp + 8192);  // mt+1
      int ysw = ((ks * 4 + q) ^ (l15 & 7)) * 8;
      bf16x8 by0A = *(const bf16x8*)&YA[l15 * 128 + ysw];
      bf16x8 by1A = *(const bf16x8*)&YA[(16 + l15) * 128 + ysw];
      bf16x8 by0B = *(const bf16x8*)&YB[l15 * 128 + ysw];
      bf16x8 by1B = *(const bf16x8*)&YB[(16 + l15) * 128 + ysw];
      acc2A[0][0] = MFMA16(wfa, by0A, acc2A[0][0]);
      acc2A[0][1] = MFMA16(wfa, by1A, acc2A[0][1]);
      acc2A[1][0] = MFMA16(wfb, by0A, acc2A[1][0]);
      acc2A[1][1] = MFMA16(wfb, by1A, acc2A[1][1]);
      acc2B[0][0] = MFMA16(wfa, by0B, acc2B[0][0]);
      acc2B[0][1] = MFMA16(wfa, by1B, acc2B[0][1]);
      acc2B[1][0] = MFMA16(wfb, by0B, acc2B[1][0]);
      acc2B[1][1] = MFMA16(wfb, by1B, acc2B[1][1]);
    }
    __builtin_amdgcn_s_setprio(0);
  };

  g1c_h(0);
  ypk();
  yst(0);                    // buf0 last read ended before B3 -- safe
  __syncthreads();           // B4: buf0 visible
#pragma unroll
  for (int h = 1; h < 4; ++h) {
    g1c_h(h);                // overlaps einsum2(h-1)
    ypk();
    einsum2(h - 1, (h - 1) & 1);   // reads buf (h-1)&1
    yst(h & 1);              // writes the OTHER buffer; its last reader
                             // (einsum2(h-2) / einsum1(1)) is fenced by the
                             // previous loop barrier / B3
    __syncthreads();         // B5..B7: buf h&1 visible
  }
  einsum2(3, 1);

  // ---- epilogue: bias2+relu in regs, fc directly from accumulators ----
  float p0A = 0.0f, p1A = 0.0f, p0B = 0.0f, p1B = 0.0f;
#pragma unroll
  for (int ot = 0; ot < 2; ++ot) {
    int ob = (2 * w + ot) * 16 + q * 4;  // o base, 4 contiguous per lane
    float4 bv = *(const float4*)&bias2[ob];
#pragma unroll
    for (int nt = 0; nt < 2; ++nt) {
      int n = nt * 16 + l15;
      float4 w0 = *(const float4*)&fc_w[n * 128 + ob];
      float4 w1v = *(const float4*)&fc_w[4096 + n * 128 + ob];
      float hA0 = fmaxf(acc2A[ot][nt][0] + bv.x, 0.0f);
      float hA1 = fmaxf(acc2A[ot][nt][1] + bv.y, 0.0f);
      float hA2 = fmaxf(acc2A[ot][nt][2] + bv.z, 0.0f);
      float hA3 = fmaxf(acc2A[ot][nt][3] + bv.w, 0.0f);
      float hB0 = fmaxf(acc2B[ot][nt][0] + bv.x, 0.0f);
      float hB1 = fmaxf(acc2B[ot][nt][1] + bv.y, 0.0f);
      float hB2 = fmaxf(acc2B[ot][nt][2] + bv.z, 0.0f);
      float hB3 = fmaxf(acc2B[ot][nt][3] + bv.w, 0.0f);
      p0A = fmaf(hA0, w0.x, fmaf(hA1, w0.y, fmaf(hA2, w0.z, fmaf(hA3, w0.w, p0A))));
      p1A = fmaf(hA0, w1v.x, fmaf(hA1, w1v.y, fmaf(hA2, w1v.z, fmaf(hA3, w1v.w, p1A))));
      p0B = fmaf(hB0, w0.x, fmaf(hB1, w0.y, fmaf(hB2, w0.z, fmaf(hB3, w0.w, p0B))));
      p1B = fmaf(hB0, w1v.x, fmaf(hB1, w1v.y, fmaf(hB2, w1v.z, fmaf(hB3, w1v.w, p1B))));
    }
  }
#pragma unroll
  for (int off = 32; off >= 1; off >>= 1) {
    p0A += __shfl_xor(p0A, off);
    p1A += __shfl_xor(p1A, off);
    p0B += __shfl_xor(p0B, off);
    p1B += __shfl_xor(p1B, off);
  }
  if (lane == 0) {
    // red overlays Ht: all waves' Ht reads (g1c_h(3)) precede the last loop
    // barrier (B7); these writes follow it.
    red[w * 4 + 0] = p0A;
    red[w * 4 + 1] = p1A;
    red[w * 4 + 2] = p0B;
    red[w * 4 + 3] = p1B;
  }
  __syncthreads();
  if (tid < 4) {
    float s = red[tid] + red[4 + tid] + red[8 + tid] + red[12 + tid] + fc_b[tid & 1];
    out[(b0 + (tid >> 1)) * 2 + (tid & 1)] = s;
  }
}

extern "C" void kernel_launch(void* const* d_in, const int* in_sizes, int n_in,
                              void* d_out, int out_size, void* d_ws, size_t ws_size,
                              hipStream_t stream) {
  const float* x        = (const float*)d_in[0];
  const float* adj      = (const float*)d_in[1];
  const float* adj_bias = (const float*)d_in[2];
  const float* w1       = (const float*)d_in[3];
  const float* b1       = (const float*)d_in[4];
  const float* w2       = (const float*)d_in[5];
  const float* b2       = (const float*)d_in[6];
  const float* fc_w     = (const float*)d_in[7];
  const float* fc_b     = (const float*)d_in[8];
  float* out = (float*)d_out;
  char* ws   = (char*)d_ws;

  prep_kernel<<<17, 256, 0, stream>>>(adj, adj_bias, w1, b1, w2, b2, ws);
  dgcnn_kernel<<<4096, 256, 0, stream>>>(x, ws, fc_w, fc_b, out);
}

// Round 13
// 173.374 us; speedup vs baseline: 1.0158x; 1.0158x over previous
//
#include <hip/hip_runtime.h>

typedef unsigned short u16;
typedef unsigned int u32;
typedef short bf16x8 __attribute__((ext_vector_type(8)));
typedef float f32x4 __attribute__((ext_vector_type(4)));
typedef u32 u32x4 __attribute__((ext_vector_type(4)));

#define MFMA16(a, b, c) __builtin_amdgcn_mfma_f32_16x16x32_bf16((a), (b), (c), 0, 0, 0)

__device__ __forceinline__ u16 f2bf(float f) {
  u32 u = __builtin_bit_cast(u32, f);
  u += 0x7FFFu + ((u >> 16) & 1u);
  return (u16)(u >> 16);
}
// packed f32x2 -> bf16x2, round-half-up (R6-proven; ties differ from RNE by
// <=1 ulp, absmax headroom 3x). NOTE (R4 post-mortem): inline-asm
// v_cvt_pk_bf16_f32 produced NaN on this toolchain -- do NOT reintroduce it.
__device__ __forceinline__ u32 pk2bf(float a, float b) {
  u32 ua = __builtin_bit_cast(u32, a) + 0x8000u;
  u32 ub = __builtin_bit_cast(u32, b) + 0x8000u;
  return (ua >> 16) | (ub & 0xFFFF0000u);
}

// ws byte offsets
#define WS_MGF   0         // bf16 [8 jt][64 lane][8 j]      B-frags of M^T   (8192 B)
#define WS_WT1F  8192      // bf16 [8 ot][2 h][4 ks][64][8]  B-frags of Wp1   (65536 B)
#define WS_WT2F  73728     // bf16 [8 mt][4 h][4 ks][64][8]  A-frags of Wp2^T (131072 B)
#define WS_B1    204800    // f32 [128]  bias1 + T0-fold
#define WS_B2    205312    // f32 [128]  bias2 + T0-fold

// NOTE on element order (kc-permutation): within each 32-wide kc chunk, the
// fragment element at (reader lane q, elem j) holds channel
//   c_local = (j>>2)*16 + q*4 + (j&3)
// chosen so the G1 producer's 8 outputs per lane are CONTIGUOUS in LDS
// (one ds_write_b128). WT1F/WT2F below are built with the same order.
__global__ void prep_kernel(const float* __restrict__ adj,
                            const float* __restrict__ adj_bias,
                            const float* __restrict__ w1,
                            const float* __restrict__ b1,
                            const float* __restrict__ w2,
                            const float* __restrict__ b2,
                            char* __restrict__ ws) {
  const int tid = threadIdx.x;
  if (blockIdx.x == 0) {
    __shared__ float sa[1024], Ls[1024], L2s[1024], L3s[1024], sdre[32];
    float bias = adj_bias[0];
    for (int i = tid; i < 1024; i += 256) sa[i] = fmaxf(adj[i] + bias, 0.0f);
    __syncthreads();
    if (tid < 32) {
      float s = 0.0f;
      for (int c = 0; c < 32; ++c) s += sa[tid * 32 + c];
      sdre[tid] = 1.0f / sqrtf(s + 1e-5f);
    }
    __syncthreads();
    for (int i = tid; i < 1024; i += 256) {
      int n = i >> 5, c = i & 31;
      Ls[i] = (n == c ? 1.0f : 0.0f) - sdre[n] * sa[i] * sdre[c];
    }
    __syncthreads();
    for (int i = tid; i < 1024; i += 256) {
      int r = i >> 5, c = i & 31;
      float s = 0.0f;
      for (int m = 0; m < 32; ++m) s += Ls[r * 32 + m] * Ls[m * 32 + c];
      L2s[i] = s;
    }
    __syncthreads();
    for (int i = tid; i < 1024; i += 256) {
      int r = i >> 5, c = i & 31;
      float s = 0.0f;
      for (int m = 0; m < 32; ++m) s += L2s[r * 32 + m] * Ls[m * 32 + c];
      L3s[i] = s;
    }
    __syncthreads();
    // M stacked [128x32]: rows 0-31 I, 32-63 L, 64-95 2L^2-I, 96-127 4L^3-3L.
    // B-fragments of M^T: MGf[jt][lane][j] = M[col=jt*16+(lane&15)][k=(lane>>4)*8+j]
    u16* MGf = (u16*)(ws + WS_MGF);
    for (int i = tid; i < 4096; i += 256) {
      int jt = i >> 9, lane = (i >> 3) & 63, j = i & 7;
      int col = jt * 16 + (lane & 15);
      int k = ((lane >> 4) << 3) + j;
      int kk = col >> 5, np = col & 31;
      float v;
      if (kk == 0)      v = (np == k) ? 1.0f : 0.0f;
      else if (kk == 1) v = Ls[np * 32 + k];
      else if (kk == 2) v = 2.0f * L2s[np * 32 + k] - (np == k ? 1.0f : 0.0f);
      else              v = 4.0f * L3s[np * 32 + k] - 3.0f * Ls[np * 32 + k];
      MGf[i] = f2bf(v);
    }
    float* B1 = (float*)(ws + WS_B1);
    float* B2 = (float*)(ws + WS_B2);
    if (tid < 128) {
      float s = b1[tid];
      for (int c = 0; c < 60; ++c) s += w1[(c * 5) * 128 + tid];
      B1[tid] = s;
    } else {
      int o = tid - 128;
      float s = b2[o];
      for (int c = 0; c < 128; ++c) s += w2[(c * 5) * 128 + o];
      B2[o] = s;
    }
  } else {
    u16* WT1F = (u16*)(ws + WS_WT1F);
    u16* WT2F = (u16*)(ws + WS_WT2F);
    int g = (blockIdx.x - 1) * 256 + tid;
    // WT1F bits: j[0:3) lane[3:9) ks[9:11) h[11:12) ot[12:15)
    // element = w1 at kterm=ks, c = h*32 + (j>>2)*16 + q*4 + (j&3) (0 if c>=60),
    // o = ot*16+(lane&15)   [kc-permuted order]
    for (int i = g; i < 32768; i += 16 * 256) {
      int j = i & 7, lane = (i >> 3) & 63, ks = (i >> 9) & 3;
      int h = (i >> 11) & 1, ot = i >> 12;
      int q = lane >> 4;
      int c = h * 32 + ((j >> 2) << 4) + q * 4 + (j & 3);
      int o = ot * 16 + (lane & 15);
      WT1F[i] = (c < 60) ? f2bf(w1[(c * 5 + ks + 1) * 128 + o]) : (u16)0;
    }
    // WT2F bits: j[0:3) lane[3:9) ks[9:11) h[11:13) mt[13:16)
    // element = w2 at kterm=ks, c2 = h*32 + (j>>2)*16 + q*4 + (j&3),
    // o = mt*16+(lane&15)   [kc-permuted order]
    for (int i = g; i < 65536; i += 16 * 256) {
      int j = i & 7, lane = (i >> 3) & 63, ks = (i >> 9) & 3;
      int h = (i >> 11) & 3, mt = i >> 13;
      int q = lane >> 4;
      int c2 = h * 32 + ((j >> 2) << 4) + q * 4 + (j & 3);
      int o = mt * 16 + (lane & 15);
      WT2F[i] = f2bf(w2[(c2 * 5 + ks + 1) * 128 + o]);
    }
  }
}

// R6 champion (session-best, 173.78 us total / ~84 us dgcnn): 2 batches/block,
// shared weight frags, batch-ILP MFMA chains, software-pipelined G1/einsum
// (G1-compute of chunk h overlaps einsum(h-1); Y written after the barrier),
// cheap round-half-up pk2bf, Ht full-rank swizzle, bounds(256,4).
// Falsified alternatives (do not revisit): bounds-5 (spills, R1/R9),
// batch-private waves (R3), contraction flip (R7/R8), Y double-buffer at
// 3 blocks/CU (R12), asm cvt_pk (R4), ypk-split/setprio (R10, null).
// LDS layouts (32768 B, 4 blocks/CU):
//   Xt [64 c][40] u16       pad-stride, 5120 B/batch
//   Ht [128 o][32] u16      slot swizzle ps = s ^ (l15&3) ^ (l15>>2)
//   Y  [32 np][128 kc] u16  16B-slot swizzle ps = s ^ (np&7); 8 KB/batch
//   Ht overlays Xt (Xt dead after layer-1 G1); red overlays Ht in epilogue.
__global__ __launch_bounds__(256, 4) void dgcnn_kernel(
    const float* __restrict__ x,
    const char* __restrict__ ws,
    const float* __restrict__ fc_w,
    const float* __restrict__ fc_b,
    float* __restrict__ out) {
  __shared__ __align__(16) char arena[32768];
  u16* XtA = (u16*)arena;             // 5120 B
  u16* XtB = (u16*)(arena + 5120);    // 5120 B
  u16* HtA = (u16*)arena;             // 8192 B (after Xt dead)
  u16* HtB = (u16*)(arena + 8192);    // 8192 B
  u16* YA  = (u16*)(arena + 16384);   // 8192 B
  u16* YB  = (u16*)(arena + 24576);   // 8192 B
  float* red = (float*)arena;         // epilogue overlay (Ht dead)

  const u16* MGf  = (const u16*)(ws + WS_MGF);
  const u16* WT1F = (const u16*)(ws + WS_WT1F);
  const u16* WT2F = (const u16*)(ws + WS_WT2F);
  const float* bias1 = (const float*)(ws + WS_B1);
  const float* bias2 = (const float*)(ws + WS_B2);

  const int tid = threadIdx.x;
  const int w = tid >> 6, lane = tid & 63;
  const int l15 = lane & 15, q = lane >> 4;
  const int b0 = blockIdx.x * 2;
  const f32x4 z4 = {0.0f, 0.0f, 0.0f, 0.0f};

  // M^T B-fragments: wave w covers M^T col tiles 2w, 2w+1 (k-term = w)
  bf16x8 mB0 = *(const bf16x8*)(MGf + ((2 * w + 0) * 64 + lane) * 8);
  bf16x8 mB1 = *(const bf16x8*)(MGf + ((2 * w + 1) * 64 + lane) * 8);

  // ---- stage x^T (both batches), coalesced float4 loads, b32 node-pair
  // writes (2-way banks = free). Threads with tc==60 write the zero rows.
  const float* xb = x + (size_t)b0 * 1920;
  {
    int tn = (tid & 15) * 2;   // node pair n, n+1
    int tc = (tid >> 4) * 4;   // channel quad c..c+3
    if (tc < 60) {
      float4 a0 = *(const float4*)(xb + tn * 60 + tc);
      float4 a1 = *(const float4*)(xb + tn * 60 + 60 + tc);
      float4 c0 = *(const float4*)(xb + 1920 + tn * 60 + tc);
      float4 c1 = *(const float4*)(xb + 1920 + tn * 60 + 60 + tc);
      *(u32*)&XtA[(tc + 0) * 40 + tn] = pk2bf(a0.x, a1.x);
      *(u32*)&XtA[(tc + 1) * 40 + tn] = pk2bf(a0.y, a1.y);
      *(u32*)&XtA[(tc + 2) * 40 + tn] = pk2bf(a0.z, a1.z);
      *(u32*)&XtA[(tc + 3) * 40 + tn] = pk2bf(a0.w, a1.w);
      *(u32*)&XtB[(tc + 0) * 40 + tn] = pk2bf(c0.x, c1.x);
      *(u32*)&XtB[(tc + 1) * 40 + tn] = pk2bf(c0.y, c1.y);
      *(u32*)&XtB[(tc + 2) * 40 + tn] = pk2bf(c0.z, c1.z);
      *(u32*)&XtB[(tc + 3) * 40 + tn] = pk2bf(c0.w, c1.w);
    } else {
#pragma unroll
      for (int j = 0; j < 4; ++j) {
        *(u32*)&XtA[(tc + j) * 40 + tn] = 0;
        *(u32*)&XtB[(tc + j) * 40 + tn] = 0;
      }
    }
  }
  __syncthreads();

  // G1 write swizzle: 16B slot (w*4+q) XOR'd with (np&7); same for both jtl.
  const int ysw_w = ((w * 4 + q) ^ (l15 & 7)) * 8;  // u16 units
  const int psr = (q ^ (l15 & 3) ^ (l15 >> 2)) * 8; // Ht read slot (layer 2)

  // G1 pipeline registers: [mtl][ct] as named vars (static indexing, rule #20)
  f32x4 gA00, gA01, gA10, gA11, gB00, gB01, gB10, gB11;

  // G1-compute from Xt (layer 1), chunk h -> g regs only (no LDS write)
  auto g1c_x = [&](int h) {
    int r0 = ((2 * h + 0) * 16 + l15) * 40 + q * 8;
    int r1 = ((2 * h + 1) * 16 + l15) * 40 + q * 8;
    bf16x8 aA0 = *(const bf16x8*)&XtA[r0];
    bf16x8 aA1 = *(const bf16x8*)&XtA[r1];
    bf16x8 aB0 = *(const bf16x8*)&XtB[r0];
    bf16x8 aB1 = *(const bf16x8*)&XtB[r1];
    gA00 = MFMA16(aA0, mB0, z4); gA01 = MFMA16(aA0, mB1, z4);
    gA10 = MFMA16(aA1, mB0, z4); gA11 = MFMA16(aA1, mB1, z4);
    gB00 = MFMA16(aB0, mB0, z4); gB01 = MFMA16(aB0, mB1, z4);
    gB10 = MFMA16(aB1, mB0, z4); gB11 = MFMA16(aB1, mB1, z4);
  };
  // G1-compute from Ht (layer 2), chunk h
  auto g1c_h = [&](int h) {
    int o20 = ((2 * h + 0) * 16 + l15) * 32 + psr;
    int o21 = ((2 * h + 1) * 16 + l15) * 32 + psr;
    bf16x8 aA0 = *(const bf16x8*)&HtA[o20];
    bf16x8 aA1 = *(const bf16x8*)&HtA[o21];
    bf16x8 aB0 = *(const bf16x8*)&HtB[o20];
    bf16x8 aB1 = *(const bf16x8*)&HtB[o21];
    gA00 = MFMA16(aA0, mB0, z4); gA01 = MFMA16(aA0, mB1, z4);
    gA10 = MFMA16(aA1, mB0, z4); gA11 = MFMA16(aA1, mB1, z4);
    gB00 = MFMA16(aB0, mB0, z4); gB01 = MFMA16(aB0, mB1, z4);
    gB10 = MFMA16(aB1, mB0, z4); gB11 = MFMA16(aB1, mB1, z4);
  };
  // pack + Y write of the held g regs (jtl=0 uses g*00/g*10, jtl=1 g*01/g*11)
  auto yw = [&]() {
    u32x4 vA = {pk2bf(gA00[0], gA00[1]), pk2bf(gA00[2], gA00[3]),
                pk2bf(gA10[0], gA10[1]), pk2bf(gA10[2], gA10[3])};
    u32x4 vB = {pk2bf(gB00[0], gB00[1]), pk2bf(gB00[2], gB00[3]),
                pk2bf(gB10[0], gB10[1]), pk2bf(gB10[2], gB10[3])};
    *(u32x4*)&YA[(0 * 16 + l15) * 128 + ysw_w] = vA;
    *(u32x4*)&YB[(0 * 16 + l15) * 128 + ysw_w] = vB;
    u32x4 wA = {pk2bf(gA01[0], gA01[1]), pk2bf(gA01[2], gA01[3]),
                pk2bf(gA11[0], gA11[1]), pk2bf(gA11[2], gA11[3])};
    u32x4 wB = {pk2bf(gB01[0], gB01[1]), pk2bf(gB01[2], gB01[3]),
                pk2bf(gB11[0], gB11[1]), pk2bf(gB11[2], gB11[3])};
    *(u32x4*)&YA[(1 * 16 + l15) * 128 + ysw_w] = wA;
    *(u32x4*)&YB[(1 * 16 + l15) * 128 + ysw_w] = wB;
  };

  // ---------------- layer 1: 2 kc-chunks, software-pipelined ----------------
  f32x4 acc1A[2][2] = {{z4, z4}, {z4, z4}};  // [nt][ot]
  f32x4 acc1B[2][2] = {{z4, z4}, {z4, z4}};
  auto einsum1 = [&](int h) {
#pragma unroll
    for (int ks = 0; ks < 4; ++ks) {
      const u16* wp = WT1F + (size_t)((((2 * w) * 2 + h) * 4 + ks) * 64 + lane) * 8;
      bf16x8 wfa = *(const bf16x8*)wp;
      bf16x8 wfb = *(const bf16x8*)(wp + 4096);  // ot+1
      int ysw = ((ks * 4 + q) ^ (l15 & 7)) * 8;
      bf16x8 a0A = *(const bf16x8*)&YA[l15 * 128 + ysw];
      bf16x8 a1A = *(const bf16x8*)&YA[(16 + l15) * 128 + ysw];
      bf16x8 a0B = *(const bf16x8*)&YB[l15 * 128 + ysw];
      bf16x8 a1B = *(const bf16x8*)&YB[(16 + l15) * 128 + ysw];
      acc1A[0][0] = MFMA16(a0A, wfa, acc1A[0][0]);
      acc1A[0][1] = MFMA16(a0A, wfb, acc1A[0][1]);
      acc1A[1][0] = MFMA16(a1A, wfa, acc1A[1][0]);
      acc1A[1][1] = MFMA16(a1A, wfb, acc1A[1][1]);
      acc1B[0][0] = MFMA16(a0B, wfa, acc1B[0][0]);
      acc1B[0][1] = MFMA16(a0B, wfb, acc1B[0][1]);
      acc1B[1][0] = MFMA16(a1B, wfa, acc1B[1][0]);
      acc1B[1][1] = MFMA16(a1B, wfb, acc1B[1][1]);
    }
  };

  g1c_x(0);
  yw();
  __syncthreads();           // Y(0) visible
  g1c_x(1);                  // overlaps einsum(0): separate pipes
  einsum1(0);
  __syncthreads();           // einsum(0) reads done
  yw();
  __syncthreads();           // Y(1) visible
  einsum1(1);

  // bias+relu -> Ht (Xt dead: all Xt reads preceded the pre-yw barriers)
#pragma unroll
  for (int ot = 0; ot < 2; ++ot) {
    int o = (2 * w + ot) * 16 + l15;
    float bv = bias1[o];
#pragma unroll
    for (int mt = 0; mt < 2; ++mt) {
      // logical n-slot s = mt*2 + (q>>1); physical = s ^ (l15&3) ^ (l15>>2)
      int ps = (mt * 2 + (q >> 1)) ^ (l15 & 3) ^ (l15 >> 2);
      int idx = o * 32 + ps * 8 + (q & 1) * 4;
      uint2 vA, vB;
      vA.x = pk2bf(fmaxf(acc1A[mt][ot][0] + bv, 0.0f), fmaxf(acc1A[mt][ot][1] + bv, 0.0f));
      vA.y = pk2bf(fmaxf(acc1A[mt][ot][2] + bv, 0.0f), fmaxf(acc1A[mt][ot][3] + bv, 0.0f));
      vB.x = pk2bf(fmaxf(acc1B[mt][ot][0] + bv, 0.0f), fmaxf(acc1B[mt][ot][1] + bv, 0.0f));
      vB.y = pk2bf(fmaxf(acc1B[mt][ot][2] + bv, 0.0f), fmaxf(acc1B[mt][ot][3] + bv, 0.0f));
      *(uint2*)&HtA[idx] = vA;
      *(uint2*)&HtB[idx] = vB;
    }
  }
  __syncthreads();           // Ht visible; also fences einsum1(1) Y-reads

  // ---------------- layer 2: 4 kc-chunks, software-pipelined ----------------
  f32x4 acc2A[2][2] = {{z4, z4}, {z4, z4}};  // [ot][nt]
  f32x4 acc2B[2][2] = {{z4, z4}, {z4, z4}};
  auto einsum2 = [&](int h) {
#pragma unroll
    for (int ks = 0; ks < 4; ++ks) {
      const u16* wp = WT2F + (size_t)((((2 * w) * 4 + h) * 4 + ks) * 64 + lane) * 8;
      bf16x8 wfa = *(const bf16x8*)wp;
      bf16x8 wfb = *(const bf16x8*)(wp + 8192);  // mt+1
      int ysw = ((ks * 4 + q) ^ (l15 & 7)) * 8;
      bf16x8 by0A = *(const bf16x8*)&YA[l15 * 128 + ysw];
      bf16x8 by1A = *(const bf16x8*)&YA[(16 + l15) * 128 + ysw];
      bf16x8 by0B = *(const bf16x8*)&YB[l15 * 128 + ysw];
      bf16x8 by1B = *(const bf16x8*)&YB[(16 + l15) * 128 + ysw];
      acc2A[0][0] = MFMA16(wfa, by0A, acc2A[0][0]);
      acc2A[0][1] = MFMA16(wfa, by1A, acc2A[0][1]);
      acc2A[1][0] = MFMA16(wfb, by0A, acc2A[1][0]);
      acc2A[1][1] = MFMA16(wfb, by1A, acc2A[1][1]);
      acc2B[0][0] = MFMA16(wfa, by0B, acc2B[0][0]);
      acc2B[0][1] = MFMA16(wfa, by1B, acc2B[0][1]);
      acc2B[1][0] = MFMA16(wfb, by0B, acc2B[1][0]);
      acc2B[1][1] = MFMA16(wfb, by1B, acc2B[1][1]);
    }
  };

  g1c_h(0);
  yw();                      // overwrites Y last read by einsum1(1) -- fenced
  __syncthreads();           // by the post-Ht barrier above; Y(0) visible now
#pragma unroll
  for (int h = 1; h < 4; ++h) {
    g1c_h(h);                // overlaps einsum2(h-1)
    einsum2(h - 1);
    __syncthreads();         // einsum2(h-1) reads done
    yw();
    __syncthreads();         // Y(h) visible
  }
  einsum2(3);

  // ---- epilogue: bias2+relu in regs, fc directly from accumulators ----
  float p0A = 0.0f, p1A = 0.0f, p0B = 0.0f, p1B = 0.0f;
#pragma unroll
  for (int ot = 0; ot < 2; ++ot) {
    int ob = (2 * w + ot) * 16 + q * 4;  // o base, 4 contiguous per lane
    float4 bv = *(const float4*)&bias2[ob];
#pragma unroll
    for (int nt = 0; nt < 2; ++nt) {
      int n = nt * 16 + l15;
      float4 w0 = *(const float4*)&fc_w[n * 128 + ob];
      float4 w1v = *(const float4*)&fc_w[4096 + n * 128 + ob];
      float hA0 = fmaxf(acc2A[ot][nt][0] + bv.x, 0.0f);
      float hA1 = fmaxf(acc2A[ot][nt][1] + bv.y, 0.0f);
      float hA2 = fmaxf(acc2A[ot][nt][2] + bv.z, 0.0f);
      float hA3 = fmaxf(acc2A[ot][nt][3] + bv.w, 0.0f);
      float hB0 = fmaxf(acc2B[ot][nt][0] + bv.x, 0.0f);
      float hB1 = fmaxf(acc2B[ot][nt][1] + bv.y, 0.0f);
      float hB2 = fmaxf(acc2B[ot][nt][2] + bv.z, 0.0f);
      float hB3 = fmaxf(acc2B[ot][nt][3] + bv.w, 0.0f);
      p0A = fmaf(hA0, w0.x, fmaf(hA1, w0.y, fmaf(hA2, w0.z, fmaf(hA3, w0.w, p0A))));
      p1A = fmaf(hA0, w1v.x, fmaf(hA1, w1v.y, fmaf(hA2, w1v.z, fmaf(hA3, w1v.w, p1A))));
      p0B = fmaf(hB0, w0.x, fmaf(hB1, w0.y, fmaf(hB2, w0.z, fmaf(hB3, w0.w, p0B))));
      p1B = fmaf(hB0, w1v.x, fmaf(hB1, w1v.y, fmaf(hB2, w1v.z, fmaf(hB3, w1v.w, p1B))));
    }
  }
#pragma unroll
  for (int off = 32; off >= 1; off >>= 1) {
    p0A += __shfl_xor(p0A, off);
    p1A += __shfl_xor(p1A, off);
    p0B += __shfl_xor(p0B, off);
    p1B += __shfl_xor(p1B, off);
  }
  if (lane == 0) {
    red[w * 4 + 0] = p0A;
    red[w * 4 + 1] = p1A;
    red[w * 4 + 2] = p0B;
    red[w * 4 + 3] = p1B;
  }
  __syncthreads();
  if (tid < 4) {
    float s = red[tid] + red[4 + tid] + red[8 + tid] + red[12 + tid] + fc_b[tid & 1];
    out[(b0 + (tid >> 1)) * 2 + (tid & 1)] = s;
  }
}

extern "C" void kernel_launch(void* const* d_in, const int* in_sizes, int n_in,
                              void* d_out, int out_size, void* d_ws, size_t ws_size,
                              hipStream_t stream) {
  const float* x        = (const float*)d_in[0];
  const float* adj      = (const float*)d_in[1];
  const float* adj_bias = (const float*)d_in[2];
  const float* w1       = (const float*)d_in[3];
  const float* b1       = (const float*)d_in[4];
  const float* w2       = (const float*)d_in[5];
  const float* b2       = (const float*)d_in[6];
  const float* fc_w     = (const float*)d_in[7];
  const float* fc_b     = (const float*)d_in[8];
  float* out = (float*)d_out;
  char* ws   = (char*)d_ws;

  prep_kernel<<<17, 256, 0, stream>>>(adj, adj_bias, w1, b1, w2, b2, ws);
  dgcnn_kernel<<<4096, 256, 0, stream>>>(x, ws, fc_w, fc_b, out);
}